// Round 1
// baseline (275.801 us; speedup 1.0000x reference)
//
#include <hip/hip_runtime.h>

// Scatter-add: out = A; for each edge e: out[index[e]] += B[e]
// N_NODES=100000, N_EDGES=1250000, D=64, all fp32, index int32.

#define D_FEAT 64

__global__ void scatter_add_kernel(const int* __restrict__ index,
                                   const float* __restrict__ B,
                                   float* __restrict__ out,
                                   long long total /* N_EDGES * D */) {
    long long i = (long long)blockIdx.x * blockDim.x + threadIdx.x;
    if (i >= total) return;
    int e = (int)(i >> 6);       // edge id  (D=64)
    int f = (int)(i & 63);       // feature id
    int node = index[e];         // wave-uniform load (all 64 lanes same e)
    atomicAdd(&out[(long long)node * D_FEAT + f], B[i]);
}

extern "C" void kernel_launch(void* const* d_in, const int* in_sizes, int n_in,
                              void* d_out, int out_size, void* d_ws, size_t ws_size,
                              hipStream_t stream) {
    const int*   index = (const int*)d_in[0];   // (N_EDGES,) int32
    const float* A     = (const float*)d_in[1]; // (N_NODES, 64) f32
    const float* B     = (const float*)d_in[2]; // (N_EDGES, 64) f32
    float*       out   = (float*)d_out;         // (N_NODES, 64) f32

    const int n_edges = in_sizes[0];
    const int n_out   = out_size;               // N_NODES * 64

    // 1) out = A  (device-to-device async copy; graph-capture safe)
    hipMemcpyAsync(out, A, (size_t)n_out * sizeof(float),
                   hipMemcpyDeviceToDevice, stream);

    // 2) atomic scatter-add of B into out
    long long total = (long long)n_edges * D_FEAT;
    int block = 256;
    long long grid = (total + block - 1) / block;
    scatter_add_kernel<<<(int)grid, block, 0, stream>>>(index, B, out, total);
}